// Round 15
// baseline (58.466 us; speedup 1.0000x reference)
//
#include <hip/hip_runtime.h>
#include <hip/hip_bf16.h>

#define SEQ 4096
#define MTOT 16384

typedef float f32x4  __attribute__((ext_vector_type(4)));
typedef float f32x16 __attribute__((ext_vector_type(16)));
typedef _Float16 f16;
typedef _Float16 f16x4 __attribute__((ext_vector_type(4)));
typedef _Float16 f16x8 __attribute__((ext_vector_type(8)));
typedef unsigned int   u32;
typedef unsigned int   u32x2 __attribute__((ext_vector_type(2)));
typedef unsigned short u16;

// ws byte offsets — Q/K/V/W in MFMA fragment-linear layout.
// Q_lin [qhalf(512)][ch(4)][lane(64)][8] : lane(l31,h) = Q[qhalf*32+l31][ch*16+h*8+j]
// K_lin [tile(512)][ch(4)][lane(64)][8]  : lane(l31,h) = K[tile*32+l31][ch*16+h*8+j]
// V_lin [tile(512)][db2][p2][lane(64)][8]
// W_lin [s(12)][step(16)][lane(64)][8]   (Wq pre-scaled by 0.125*log2e)
static constexpr size_t QL_B   = 0;           // 2MB
static constexpr size_t KL_B   = 2u << 20;    // 2MB
static constexpr size_t VL_B   = 4u << 20;    // 2MB
static constexpr size_t WL_B   = 6u << 20;    // 192KB

__device__ __forceinline__ u16 h16(float v) { return __builtin_bit_cast(u16, (f16)v); }
__device__ __forceinline__ u32 pkrtz(float a, float b) {
  return __builtin_bit_cast(u32, __builtin_amdgcn_cvt_pkrtz(a, b));
}
__device__ __forceinline__ float ex2(float x) { return __builtin_amdgcn_exp2f(x); }
__device__ __forceinline__ void gl16(const u16* g, u16* l) {
  __builtin_amdgcn_global_load_lds((const __attribute__((address_space(1))) void*)g,
                                   (__attribute__((address_space(3))) void*)l, 16, 0, 0);
}

// ---------------- W fp32 -> fragment-linear fp16 ----------------
__global__ __launch_bounds__(256) void wconv_kernel(const float* __restrict__ Wq,
                                                    const float* __restrict__ Wk,
                                                    const float* __restrict__ Wv,
                                                    u16* __restrict__ wlin) {
  const float QSC = 0.18033688011112042f;  // 0.125 * log2(e)
  int e = blockIdx.x * 256 + threadIdx.x;
  int flat = e * 4;
  int colg = flat >> 9;
  int k0   = flat & 511;
  int mat  = colg >> 6;
  const float* W = (mat == 0) ? Wq : (mat == 1 ? Wk : Wv);
  f32x4 v = *(const f32x4*)(W + (size_t)(colg & 63) * 512 + k0);
  if (mat == 0) v *= QSC;
  int s = colg >> 4, r16 = colg & 15;
  int step = k0 >> 5, g = (k0 & 31) >> 3, jb = k0 & 7;
  __attribute__((aligned(8))) u16 b[4];
#pragma unroll
  for (int j = 0; j < 4; ++j) b[j] = h16(v[j]);
  *(uint2*)(wlin + ((size_t)(s * 16 + step) * 64 + g * 16 + r16) * 8 + jb) = *(uint2*)b;
}

// ---------------- QKV projection (unchanged) ----------------
__global__ __launch_bounds__(256, 4) void proj_kernel(const float* __restrict__ x,
                                                      const u16* __restrict__ wlin,
                                                      u16* __restrict__ ws) {
  __shared__ __attribute__((aligned(16))) u16 xl[8192];
  float* scr = (float*)xl;

  const int tid  = threadIdx.x;
  const int blk  = blockIdx.x;
  const int lane = tid & 63;
  const int ng   = tid >> 6;
  const int r16  = lane & 15;
  const int g    = lane >> 4;
  const int m0   = blk * 16;

#pragma unroll
  for (int i = 0; i < 8; ++i) {
    int f = tid * 4 + i * 1024;
    int row = f >> 9, k0 = f & 511;
    f32x4 v = *(const f32x4*)(x + (size_t)m0 * 512 + f);
    __attribute__((aligned(8))) u16 b[4];
#pragma unroll
    for (int j = 0; j < 4; ++j) b[j] = h16(v[j]);
    int ln = ((k0 & 31) >> 3) * 16 + row;
    *(uint2*)(xl + ((size_t)(k0 >> 5) * 64 + ln) * 8 + (k0 & 7)) = *(uint2*)b;
  }
  __syncthreads();

  f32x4 acc[3];
#pragma unroll
  for (int s = 0; s < 3; ++s) acc[s] = (f32x4){0.f, 0.f, 0.f, 0.f};

#pragma unroll 2
  for (int step = 0; step < 16; ++step) {
    f16x8 a = *(const f16x8*)(xl + ((size_t)step * 64 + lane) * 8);
#pragma unroll
    for (int s = 0; s < 3; ++s) {
      int sg = ng * 3 + s;
      f16x8 b = *(const f16x8*)(wlin + ((size_t)(sg * 16 + step) * 64 + lane) * 8);
      acc[s] = __builtin_amdgcn_mfma_f32_16x16x32_f16(a, b, acc[s], 0, 0, 0);
    }
  }
  __syncthreads();

#pragma unroll
  for (int s = 0; s < 3; ++s)
#pragma unroll
    for (int rr = 0; rr < 4; ++rr)
      scr[(g * 4 + rr) * 193 + ng * 48 + s * 16 + r16] = acc[s][rr];
  __syncthreads();

  u16* Ql = ws + (QL_B >> 1);
  u16* Kl = ws + (KL_B >> 1);
  u16* Vl = ws + (VL_B >> 1);
  const int batch = m0 >> 12;
  const int tile  = (m0 >> 5) & 127;
  const int half  = (m0 >> 4) & 1;

  {
    int t2 = tid & 127;
    int r  = t2 & 15, hh = (t2 >> 4) & 1, ch = t2 >> 5;
    int l31 = half * 16 + r;
    __attribute__((aligned(16))) u16 b[8];
    if (tid < 128) {
#pragma unroll
      for (int j = 0; j < 8; ++j) b[j] = h16(scr[r * 193 + 64 + ch * 16 + hh * 8 + j]);
      *(uint4*)(Kl + ((size_t)((batch * 128 + tile) * 4 + ch) * 64 + hh * 32 + l31) * 8) =
          *(uint4*)b;
    } else {
#pragma unroll
      for (int j = 0; j < 8; ++j) b[j] = h16(scr[r * 193 + ch * 16 + hh * 8 + j]);
      int qhalf = (m0 >> 5);
      *(uint4*)(Ql + ((size_t)(qhalf * 4 + ch) * 64 + hh * 32 + l31) * 8) = *(uint4*)b;
    }
  }
  {
    int z = tid & 1, l31 = (tid >> 1) & 31, hh = (tid >> 6) & 1, db = tid >> 7;
    int d = db * 32 + l31;
    __attribute__((aligned(8))) u16 b[4];
#pragma unroll
    for (int j = 0; j < 4; ++j) b[j] = h16(scr[(8 * z + 4 * hh + j) * 193 + 128 + d]);
    *(uint2*)(Vl + ((size_t)(((batch * 128 + tile) * 2 + db) * 2 + half) * 64 + hh * 32 + l31) *
                       8 + z * 4) = *(uint2*)b;
  }
}

// ---------------- flash attention: dual-tile ILP, wave-private pipeline ----------------
// 512 blocks (XCD-bijective) x 256 thr (4 waves). Block = 32 q-rows; wave w owns kv
// quarter (16 PAIRS of 32-kv tiles). K pair -> private 8KB LDS dbuf (gl16); V pair ->
// register dbuf. Counted vmcnt(16), zero main-loop barriers. Per pair: QK0,QK1 ->
// joint defer-max -> 32 ex2 -> PV0,PV1; l accumulated by ones-MFMA (no VALU sums).
__global__ __launch_bounds__(256, 2) void attn_kernel(const u16* __restrict__ ws,
                                                      float* __restrict__ out) {
  __shared__ __attribute__((aligned(16))) u16 kb[4][2][4096];  // 64KB: per-wave K pair-dbuf

  const int tid  = threadIdx.x;
  const int w    = tid >> 6;
  const int lane = tid & 63;
  const int l31  = lane & 31;
  const int h    = lane >> 5;
  const int bx   = blockIdx.x;
  const int qb   = (bx & 7) * 64 + (bx >> 3);  // bijective: XCD gets contiguous q range
  const int bb   = qb >> 7;                    // batch

  const u16* Ql = ws + (QL_B >> 1);
  const u16* Kl = ws + (KL_B >> 1);
  const u16* Vl = ws + (VL_B >> 1);

  f16x8 qf[4];
#pragma unroll
  for (int ch = 0; ch < 4; ++ch)
    qf[ch] = *(const f16x8*)(Ql + ((size_t)(qb * 4 + ch) * 64 + lane) * 8);

  f32x16 oacc[2], lacc;
#pragma unroll
  for (int db = 0; db < 2; ++db)
#pragma unroll
    for (int r = 0; r < 16; ++r) oacc[db][r] = 0.f;
#pragma unroll
  for (int r = 0; r < 16; ++r) lacc[r] = 0.f;
  float mrun = -INFINITY;
  const float RTHR = 11.0f;
  const f16x4 ones = {(f16)1.f, (f16)1.f, (f16)1.f, (f16)1.f};

  const int t0 = bb * 128 + w * 32;  // wave's private 32-tile kv range (16 pairs)
  u16* b0 = &kb[w][0][0];
  u16* b1 = &kb[w][1][0];

  auto stageK = [&](u16* buf, int t) {  // stage pair (tiles t, t+1): 8 gl16
#pragma unroll
    for (int u = 0; u < 2; ++u)
#pragma unroll
      for (int c = 0; c < 4; ++c)
        gl16(Kl + (size_t)(t + u) * 2048 + c * 512 + lane * 8, buf + u * 2048 + c * 512);
  };
  f16x8 vA[2][2][2], vB[2][2][2];  // [tile][db][pp]
  auto loadV = [&](f16x8(&vv)[2][2][2], int t) {  // 8 b128
#pragma unroll
    for (int u = 0; u < 2; ++u)
#pragma unroll
      for (int db = 0; db < 2; ++db)
#pragma unroll
        for (int pp = 0; pp < 2; ++pp)
          vv[u][db][pp] =
              *(const f16x8*)(Vl + (size_t)(t + u) * 2048 + ((db * 2 + pp) * 64 + lane) * 8);
  };

  auto body = [&](u16* cb, u16* nb, f16x8(&vc)[2][2][2], f16x8(&vn)[2][2][2], int t,
                  bool last) {
    if (!last) {
      stageK(nb, t + 2);
      loadV(vn, t + 2);
      asm volatile("s_waitcnt vmcnt(16)" ::: "memory");  // current pair's 16 done
    } else {
      asm volatile("s_waitcnt vmcnt(0)" ::: "memory");
    }
    __builtin_amdgcn_sched_barrier(0);

    // QK for both tiles (independent chains)
    f32x16 sac0, sac1;
#pragma unroll
    for (int r = 0; r < 16; ++r) { sac0[r] = 0.f; sac1[r] = 0.f; }
    f16x8 ka0[4], ka1[4];
#pragma unroll
    for (int ch = 0; ch < 4; ++ch) ka0[ch] = *(const f16x8*)(cb + (ch * 64 + lane) * 8);
#pragma unroll
    for (int ch = 0; ch < 4; ++ch)
      ka1[ch] = *(const f16x8*)(cb + 2048 + (ch * 64 + lane) * 8);
#pragma unroll
    for (int ch = 0; ch < 4; ++ch)
      sac0 = __builtin_amdgcn_mfma_f32_32x32x16_f16(ka0[ch], qf[ch], sac0, 0, 0, 0);
#pragma unroll
    for (int ch = 0; ch < 4; ++ch)
      sac1 = __builtin_amdgcn_mfma_f32_32x32x16_f16(ka1[ch], qf[ch], sac1, 0, 0, 0);

    // joint tree max over both tiles
    float t16[16];
#pragma unroll
    for (int r = 0; r < 16; ++r) t16[r] = fmaxf(sac0[r], sac1[r]);
#pragma unroll
    for (int r = 0; r < 8; ++r) t16[r] = fmaxf(t16[r], t16[r + 8]);
#pragma unroll
    for (int r = 0; r < 4; ++r) t16[r] = fmaxf(t16[r], t16[r + 4]);
    float mt = fmaxf(fmaxf(t16[0], t16[1]), fmaxf(t16[2], t16[3]));
    if (__any(mt > mrun + RTHR)) {
      float mtw  = fmaxf(mt, __shfl_xor(mt, 32));
      float nm   = fmaxf(mrun, mtw);
      float corr = ex2(mrun - nm);
      mrun = nm;
#pragma unroll
      for (int db = 0; db < 2; ++db)
#pragma unroll
        for (int r = 0; r < 16; ++r) oacc[db][r] *= corr;
#pragma unroll
      for (int r = 0; r < 16; ++r) lacc[r] *= corr;
    }
#pragma unroll
    for (int r = 0; r < 16; ++r) sac0[r] = ex2(sac0[r] - mrun);
#pragma unroll
    for (int r = 0; r < 16; ++r) sac1[r] = ex2(sac1[r] - mrun);

    // P -> B-fragments (no cross-lane ops)
    f16x4 pb0[4], pb1[4];
#pragma unroll
    for (int c = 0; c < 4; ++c) {
      u32x2 k0, k1;
      k0[0] = pkrtz(sac0[4 * c + 0], sac0[4 * c + 1]);
      k0[1] = pkrtz(sac0[4 * c + 2], sac0[4 * c + 3]);
      k1[0] = pkrtz(sac1[4 * c + 0], sac1[4 * c + 1]);
      k1[1] = pkrtz(sac1[4 * c + 2], sac1[4 * c + 3]);
      pb0[c] = __builtin_bit_cast(f16x4, k0);
      pb1[c] = __builtin_bit_cast(f16x4, k1);
    }

    // l row-sums on the MFMA pipe (replaces 62 VALU adds + final shfl)
#pragma unroll
    for (int c = 0; c < 4; ++c)
      lacc = __builtin_amdgcn_mfma_f32_32x32x8f16(ones, pb0[c], lacc, 0, 0, 0);
#pragma unroll
    for (int c = 0; c < 4; ++c)
      lacc = __builtin_amdgcn_mfma_f32_32x32x8f16(ones, pb1[c], lacc, 0, 0, 0);

    // O^T += V^T * P^T for both tiles
#pragma unroll
    for (int db = 0; db < 2; ++db)
#pragma unroll
      for (int pp = 0; pp < 2; ++pp) {
        f16x4 vlo0 = __builtin_shufflevector(vc[0][db][pp], vc[0][db][pp], 0, 1, 2, 3);
        f16x4 vhi0 = __builtin_shufflevector(vc[0][db][pp], vc[0][db][pp], 4, 5, 6, 7);
        oacc[db] = __builtin_amdgcn_mfma_f32_32x32x8f16(vlo0, pb0[2 * pp], oacc[db], 0, 0, 0);
        oacc[db] = __builtin_amdgcn_mfma_f32_32x32x8f16(vhi0, pb0[2 * pp + 1], oacc[db], 0, 0, 0);
        f16x4 vlo1 = __builtin_shufflevector(vc[1][db][pp], vc[1][db][pp], 0, 1, 2, 3);
        f16x4 vhi1 = __builtin_shufflevector(vc[1][db][pp], vc[1][db][pp], 4, 5, 6, 7);
        oacc[db] = __builtin_amdgcn_mfma_f32_32x32x8f16(vlo1, pb1[2 * pp], oacc[db], 0, 0, 0);
        oacc[db] = __builtin_amdgcn_mfma_f32_32x32x8f16(vhi1, pb1[2 * pp + 1], oacc[db], 0, 0, 0);
      }
  };

  stageK(b0, t0);
  loadV(vA, t0);
#pragma unroll 1
  for (int p = 0; p < 8; ++p) {
    body(b0, b1, vA, vB, t0 + 4 * p, false);
    body(b1, b0, vB, vA, t0 + 4 * p + 2, p == 7);
  }

  float lrun = lacc[0];  // all regs/lanes of a column hold the full sum

  // ---- in-LDS 4-wave merge (kb reused: po[4][32][68] @0, mls[4][32][2] @36864B) ----
  __syncthreads();
  float* po  = (float*)&kb[0][0][0];
  float* mls = (float*)((char*)&kb[0][0][0] + 36864);
  if (h == 0) {
    mls[(w * 32 + l31) * 2 + 0] = mrun;
    mls[(w * 32 + l31) * 2 + 1] = lrun;
  }
  __syncthreads();

  float mg = -INFINITY;
#pragma unroll
  for (int ww = 0; ww < 4; ++ww) mg = fmaxf(mg, mls[(ww * 32 + l31) * 2]);
  float wgt = ex2(mrun - mg);
#pragma unroll
  for (int db = 0; db < 2; ++db)
#pragma unroll
    for (int g = 0; g < 4; ++g) {
      f32x4 v = {oacc[db][4 * g + 0] * wgt, oacc[db][4 * g + 1] * wgt,
                 oacc[db][4 * g + 2] * wgt, oacc[db][4 * g + 3] * wgt};
      *(f32x4*)(po + (size_t)(w * 32 + l31) * 68 + db * 32 + 8 * g + 4 * h) = v;
    }
  __syncthreads();

#pragma unroll
  for (int i = 0; i < 2; ++i) {
    int idx = tid + i * 256;        // [0,512): 32 rows x 16 col-groups
    int q = idx >> 4, c4 = (idx & 15) * 4;
    float m2 = -INFINITY;
#pragma unroll
    for (int ww = 0; ww < 4; ++ww) m2 = fmaxf(m2, mls[(ww * 32 + q) * 2]);
    float l2 = 0.f;
#pragma unroll
    for (int ww = 0; ww < 4; ++ww)
      l2 += mls[(ww * 32 + q) * 2 + 1] * ex2(mls[(ww * 32 + q) * 2] - m2);
    f32x4 s = (f32x4){0.f, 0.f, 0.f, 0.f};
#pragma unroll
    for (int ww = 0; ww < 4; ++ww) s += *(const f32x4*)(po + (size_t)(ww * 32 + q) * 68 + c4);
    s *= (1.f / l2);
    *(f32x4*)(out + (size_t)(qb * 32 + q) * 64 + c4) = s;
  }
}

extern "C" void kernel_launch(void* const* d_in, const int* in_sizes, int n_in,
                              void* d_out, int out_size, void* d_ws, size_t ws_size,
                              hipStream_t stream) {
  const float* x  = (const float*)d_in[0];
  const float* Wq = (const float*)d_in[1];
  const float* Wk = (const float*)d_in[2];
  const float* Wv = (const float*)d_in[3];
  u16* ws = (u16*)d_ws;
  (void)in_sizes; (void)n_in; (void)out_size; (void)ws_size;

  wconv_kernel<<<96, 256, 0, stream>>>(Wq, Wk, Wv, ws + (WL_B >> 1));
  proj_kernel<<<1024, 256, 0, stream>>>(x, ws + (WL_B >> 1), ws);
  attn_kernel<<<512, 256, 0, stream>>>(ws, (float*)d_out);
}